// Round 4
// baseline (2800.146 us; speedup 1.0000x reference)
//
#include <hip/hip_runtime.h>

typedef __bf16 bf16;
typedef __bf16 bf16x8 __attribute__((ext_vector_type(8)));
typedef float floatx4 __attribute__((ext_vector_type(4)));

#define MFMA16(a, b, c) __builtin_amdgcn_mfma_f32_16x16x32_bf16((a), (b), (c), 0, 0, 0)

// B=2, S=4096, D=768, H=12, DH=64, W=128, nc=32, DFF=3072, L=4
#define NEG_SENT -30000.0f

// flag: 1 = inputs are bf16, 0 = inputs are fp32
__device__ __forceinline__ float ldin(const void* p, size_t i, int isb)
{
    return isb ? (float)((const bf16*)p)[i] : ((const float*)p)[i];
}

// ---------------- dtype sniff ----------------
__global__ __launch_bounds__(256) void sniff_kernel(const unsigned short* __restrict__ s,
                                                    int* __restrict__ flag)
{
    __shared__ int cnt;
    if (threadIdx.x == 0) cnt = 0;
    __syncthreads();
    int good = 0;
    #pragma unroll
    for (int t = 0; t < 16; ++t) {
        unsigned short h = s[threadIdx.x * 16 + t];  // first 4096 halfwords of src
        int e = (h >> 7) & 0xFF;
        if (h == 0 || (e >= 96 && e <= 158)) good++;  // bf16-sane: |x| in [2^-31, 2^31] or 0
    }
    atomicAdd(&cnt, good);
    __syncthreads();
    if (threadIdx.x == 0) *flag = (cnt >= 3700) ? 1 : 0;
    // fp32 sniffed as bf16: mantissa-low halfwords random -> ~62% sane -> flag=0
}

// ---------------- convert -> fp32 (flag-dispatched) ----------------
__global__ __launch_bounds__(256) void cvt32_kernel(const void* __restrict__ s,
                                                    float* __restrict__ d, int n,
                                                    const int* __restrict__ flag)
{
    const int isb = *flag;
    int stride = gridDim.x * 256;
    for (int i = blockIdx.x * 256 + threadIdx.x; i < n; i += stride)
        d[i] = ldin(s, i, isb);
}

// ---------------- transpose src[eoff + K][N] -> dst[N][K] (bf16 out) ----------------
__global__ __launch_bounds__(256) void transpose_kernel(const void* __restrict__ src,
                                                        size_t eoff,
                                                        bf16* __restrict__ dst,
                                                        int K, int N,
                                                        const int* __restrict__ flag)
{
    __shared__ bf16 tile[64][65];
    const int isb = *flag;
    const int n0 = blockIdx.x * 64, k0 = blockIdx.y * 64;
    const int tid = threadIdx.x;
    #pragma unroll
    for (int it = 0; it < 16; ++it) {
        int idx = it * 256 + tid;
        int r = idx >> 6, c = idx & 63;
        tile[r][c] = (bf16)ldin(src, eoff + (size_t)(k0 + r) * N + (n0 + c), isb);
    }
    __syncthreads();
    #pragma unroll
    for (int it = 0; it < 16; ++it) {
        int idx = it * 256 + tid;
        int r = idx >> 6, c = idx & 63;
        dst[(size_t)(n0 + r) * K + (k0 + c)] = tile[c][r];
    }
}

// ---------------- concat QKV biases -> [L][2304] fp32 ----------------
__global__ __launch_bounds__(256) void concat_bias_kernel(const void* __restrict__ bq,
                                                          const void* __restrict__ bk,
                                                          const void* __restrict__ bv,
                                                          float* __restrict__ dst,
                                                          const int* __restrict__ flag)
{
    const int isb = *flag;
    int i = blockIdx.x * 256 + threadIdx.x;
    if (i >= 4 * 2304) return;
    int layer = i / 2304, c = i % 2304;
    float v;
    if (c < 768)       v = ldin(bq, layer * 768 + c, isb);
    else if (c < 1536) v = ldin(bk, layer * 768 + c - 768, isb);
    else               v = ldin(bv, layer * 768 + c - 1536, isb);
    dst[i] = v;
}

// ---------------- GEMM: C = A[M][K] @ Bt[N][K]^T + bias ----------------
// A is fp32 (a_f32=1) or bf16; converted to bf16 during LDS staging.
// mode 0: outb = bf16((acc+bias) * (col<scale_cols ? 0.125 : 1))
// mode 1: outb = bf16(relu(acc+bias))
// mode 2: outf += acc + bias   (fp32 residual RMW, same-thread)
__global__ __launch_bounds__(256, 2) void gemm_kernel(
    const void* __restrict__ A, int a_f32, const bf16* __restrict__ Bt,
    const float* __restrict__ bias,
    bf16* __restrict__ outb, float* __restrict__ outf,
    int M, int N, int K, int mode, int scale_cols)
{
    __shared__ __align__(16) bf16 As[128 * 72];  // [m][k], k-stride 72 (2-way conflict = free)
    __shared__ __align__(16) bf16 Bs[128 * 72];  // [n][k]

    const int tid = threadIdx.x;
    const int m0 = blockIdx.y * 128, n0 = blockIdx.x * 128;
    const int lane = tid & 63, wave = tid >> 6;
    const int wr = (wave >> 1) * 64, wc = (wave & 1) * 64;
    const int l16 = lane & 15, quad = lane >> 4;

    floatx4 acc[4][4];
    #pragma unroll
    for (int i = 0; i < 4; ++i)
        #pragma unroll
        for (int j = 0; j < 4; ++j)
            #pragma unroll
            for (int r = 0; r < 4; ++r) acc[i][j][r] = 0.f;

    for (int k0 = 0; k0 < K; k0 += 64) {
        #pragma unroll
        for (int it = 0; it < 4; ++it) {
            int chunk = it * 256 + tid;
            int row = chunk >> 3, c8 = (chunk & 7) * 8;
            size_t off = (size_t)(m0 + row) * K + k0 + c8;
            if (a_f32) {
                const float* Af = (const float*)A;
                float4 f0 = *(const float4*)&Af[off];
                float4 f1 = *(const float4*)&Af[off + 4];
                bf16x8 v;
                v[0] = (bf16)f0.x; v[1] = (bf16)f0.y; v[2] = (bf16)f0.z; v[3] = (bf16)f0.w;
                v[4] = (bf16)f1.x; v[5] = (bf16)f1.y; v[6] = (bf16)f1.z; v[7] = (bf16)f1.w;
                *(bf16x8*)&As[row * 72 + c8] = v;
            } else {
                *(uint4*)&As[row * 72 + c8] = *(const uint4*)&((const bf16*)A)[off];
            }
            *(uint4*)&Bs[row * 72 + c8] = *(const uint4*)&Bt[(size_t)(n0 + row) * K + k0 + c8];
        }
        __syncthreads();
        #pragma unroll
        for (int kk = 0; kk < 64; kk += 32) {
            bf16x8 af[4], bfv[4];
            #pragma unroll
            for (int i = 0; i < 4; ++i) af[i]  = *(const bf16x8*)&As[(wr + i * 16 + l16) * 72 + kk + quad * 8];
            #pragma unroll
            for (int j = 0; j < 4; ++j) bfv[j] = *(const bf16x8*)&Bs[(wc + j * 16 + l16) * 72 + kk + quad * 8];
            #pragma unroll
            for (int i = 0; i < 4; ++i)
                #pragma unroll
                for (int j = 0; j < 4; ++j)
                    acc[i][j] = MFMA16(af[i], bfv[j], acc[i][j]);
        }
        __syncthreads();
    }

    #pragma unroll
    for (int j = 0; j < 4; ++j) {
        int col = n0 + wc + j * 16 + l16;
        float bs = bias[col];
        float alpha = (col < scale_cols) ? 0.125f : 1.0f;
        #pragma unroll
        for (int i = 0; i < 4; ++i) {
            #pragma unroll
            for (int r = 0; r < 4; ++r) {
                int row = m0 + wr + i * 16 + quad * 4 + r;
                size_t idx = (size_t)row * N + col;
                float v = (acc[i][j][r] + bs) * alpha;
                if (mode == 0)      outb[idx] = (bf16)v;
                else if (mode == 1) outb[idx] = (bf16)fmaxf(v, 0.f);
                else                outf[idx] += v;
            }
        }
    }
}

// ---------------- banded flash attention: x (fp32) += attn ----------------
// qkv: [B*S][2304] bf16 (Q pre-scaled 1/8 | K | V). grid (nc=32, H=12, B=2).
__global__ __launch_bounds__(256, 1) void attn_kernel(const bf16* __restrict__ qkv,
                                                      float* __restrict__ x)
{
    __shared__ __align__(16) bf16 Qs[128 * 72];   // [q][d]
    __shared__ __align__(16) bf16 Ks[128 * 72];   // [key][d]
    __shared__ __align__(16) bf16 Vt[64 * 136];   // [d][key]  (B-operand layout)
    __shared__ __align__(16) bf16 Ps[128 * 136];  // [q][key]  (A-operand layout)

    const int c = blockIdx.x, h = blockIdx.y, b = blockIdx.z;
    const int tid = threadIdx.x;
    const int lane = tid & 63, w = tid >> 6;
    const int l16 = lane & 15, quad = lane >> 4;
    const size_t rowbase = (size_t)(b * 4096 + c * 128);

    #pragma unroll
    for (int it = 0; it < 4; ++it) {
        int chunk = it * 256 + tid;
        int row = chunk >> 3, c8 = (chunk & 7) * 8;
        *(uint4*)&Qs[row * 72 + c8] = *(const uint4*)&qkv[(rowbase + row) * 2304 + h * 64 + c8];
    }

    floatx4 o[2][4], mr[2], lr[2];
    #pragma unroll
    for (int i = 0; i < 2; ++i) {
        #pragma unroll
        for (int r = 0; r < 4; ++r) { mr[i][r] = NEG_SENT; lr[i][r] = 0.f; }
        #pragma unroll
        for (int tv = 0; tv < 4; ++tv)
            #pragma unroll
            for (int r = 0; r < 4; ++r) o[i][tv][r] = 0.f;
    }

    const int t0 = (c == 0) ? 1 : 0;
    const int t1 = (c == 31) ? 1 : 2;
    for (int t = t0; t <= t1; ++t) {
        const size_t kb = (size_t)(b * 4096 + c * 128 + (t - 1) * 128);
        __syncthreads();  // prev iteration's readers done (also covers Qs on first iter)
        #pragma unroll
        for (int it = 0; it < 4; ++it) {
            int chunk = it * 256 + tid;
            int row = chunk >> 3, c8 = (chunk & 7) * 8;
            *(uint4*)&Ks[row * 72 + c8] = *(const uint4*)&qkv[(kb + row) * 2304 + 768 + h * 64 + c8];
        }
        for (int idx = tid; idx < 8192; idx += 256) {
            int key = idx >> 6, dh = idx & 63;
            Vt[dh * 136 + key] = qkv[(kb + key) * 2304 + 1536 + h * 64 + dh];
        }
        __syncthreads();

        // S = Q K^T
        floatx4 st[2][8];
        #pragma unroll
        for (int i = 0; i < 2; ++i)
            #pragma unroll
            for (int j = 0; j < 8; ++j)
                #pragma unroll
                for (int r = 0; r < 4; ++r) st[i][j][r] = 0.f;
        #pragma unroll
        for (int kk = 0; kk < 64; kk += 32) {
            bf16x8 aq0 = *(const bf16x8*)&Qs[(w * 32 + l16) * 72 + kk + quad * 8];
            bf16x8 aq1 = *(const bf16x8*)&Qs[(w * 32 + 16 + l16) * 72 + kk + quad * 8];
            #pragma unroll
            for (int j = 0; j < 8; ++j) {
                bf16x8 bk = *(const bf16x8*)&Ks[(j * 16 + l16) * 72 + kk + quad * 8];
                st[0][j] = MFMA16(aq0, bk, st[0][j]);
                st[1][j] = MFMA16(aq1, bk, st[1][j]);
            }
        }
        // band mask: t=0 -> ki>=qi, t=2 -> ki<=qi
        if (t != 1) {
            #pragma unroll
            for (int i = 0; i < 2; ++i)
                #pragma unroll
                for (int j = 0; j < 8; ++j)
                    #pragma unroll
                    for (int r = 0; r < 4; ++r) {
                        int qi = w * 32 + i * 16 + quad * 4 + r;
                        int ki = j * 16 + l16;
                        bool valid = (t == 0) ? (ki >= qi) : (ki <= qi);
                        if (!valid) st[i][j][r] = NEG_SENT;
                    }
        }
        // online softmax (row lives across the 16 lanes of a quad)
        #pragma unroll
        for (int i = 0; i < 2; ++i) {
            floatx4 mx = st[i][0];
            #pragma unroll
            for (int j = 1; j < 8; ++j)
                #pragma unroll
                for (int r = 0; r < 4; ++r) mx[r] = fmaxf(mx[r], st[i][j][r]);
            #pragma unroll
            for (int r = 0; r < 4; ++r) {
                float v = mx[r];
                #pragma unroll
                for (int off = 1; off < 16; off <<= 1) v = fmaxf(v, __shfl_xor(v, off, 64));
                mx[r] = v;
            }
            floatx4 scale;
            #pragma unroll
            for (int r = 0; r < 4; ++r) {
                float mnew = fmaxf(mr[i][r], mx[r]);
                scale[r] = __expf(mr[i][r] - mnew);
                mr[i][r] = mnew;
            }
            floatx4 psum;
            #pragma unroll
            for (int r = 0; r < 4; ++r) psum[r] = 0.f;
            #pragma unroll
            for (int j = 0; j < 8; ++j)
                #pragma unroll
                for (int r = 0; r < 4; ++r) {
                    float p = __expf(st[i][j][r] - mr[i][r]);
                    psum[r] += p;
                    Ps[(w * 32 + i * 16 + quad * 4 + r) * 136 + j * 16 + l16] = (bf16)p;
                }
            #pragma unroll
            for (int r = 0; r < 4; ++r) {
                float v = psum[r];
                #pragma unroll
                for (int off = 1; off < 16; off <<= 1) v += __shfl_xor(v, off, 64);
                lr[i][r] = lr[i][r] * scale[r] + v;
            }
            #pragma unroll
            for (int tv = 0; tv < 4; ++tv)
                #pragma unroll
                for (int r = 0; r < 4; ++r) o[i][tv][r] *= scale[r];
        }
        __syncthreads();  // publish Ps (defensive; rows are wave-private)
        // O += P V
        #pragma unroll
        for (int kk = 0; kk < 128; kk += 32) {
            bf16x8 ap0 = *(const bf16x8*)&Ps[(w * 32 + l16) * 136 + kk + quad * 8];
            bf16x8 ap1 = *(const bf16x8*)&Ps[(w * 32 + 16 + l16) * 136 + kk + quad * 8];
            #pragma unroll
            for (int tv = 0; tv < 4; ++tv) {
                bf16x8 bv = *(const bf16x8*)&Vt[(tv * 16 + l16) * 136 + kk + quad * 8];
                o[0][tv] = MFMA16(ap0, bv, o[0][tv]);
                o[1][tv] = MFMA16(ap1, bv, o[1][tv]);
            }
        }
    }

    // epilogue: normalize, residual add into fp32 x (disjoint columns per h)
    #pragma unroll
    for (int i = 0; i < 2; ++i)
        #pragma unroll
        for (int r = 0; r < 4; ++r) {
            int srow = w * 32 + i * 16 + quad * 4 + r;
            size_t base = (rowbase + srow) * 768 + h * 64;
            float inv = 1.f / lr[i][r];
            #pragma unroll
            for (int tv = 0; tv < 4; ++tv) {
                size_t idx = base + tv * 16 + l16;
                x[idx] += o[i][tv][r] * inv;
            }
        }
}

// ---------------- LayerNorm D=768, fp32 in/out (in-place safe) ----------------
__global__ __launch_bounds__(256) void ln_kernel(const float* in,
                                                 const float* __restrict__ g,
                                                 const float* __restrict__ be,
                                                 float* out)
{
    const int wv = threadIdx.x >> 6, lane = threadIdx.x & 63;
    const size_t row = (size_t)blockIdx.x * 4 + wv;
    const float* r = in + row * 768;
    float v[12], s = 0.f, sq = 0.f;
    #pragma unroll
    for (int j = 0; j < 12; ++j) {
        float t = r[j * 64 + lane];
        v[j] = t; s += t; sq += t * t;
    }
    #pragma unroll
    for (int off = 1; off < 64; off <<= 1) {
        s += __shfl_xor(s, off, 64);
        sq += __shfl_xor(sq, off, 64);
    }
    const float mu = s * (1.f / 768.f);
    const float var = sq * (1.f / 768.f) - mu * mu;
    const float rs = rsqrtf(var + 1e-6f);
    #pragma unroll
    for (int j = 0; j < 12; ++j) {
        int col = j * 64 + lane;
        out[row * 768 + col] = (v[j] - mu) * rs * g[col] + be[col];
    }
}

// ---------------- final LayerNorm -> d_out in flag-selected dtype ----------------
__global__ __launch_bounds__(256) void ln_final_kernel(const float* __restrict__ in,
                                                       const float* __restrict__ g,
                                                       const float* __restrict__ be,
                                                       void* __restrict__ out,
                                                       const int* __restrict__ flag)
{
    const int isb = *flag;
    const int wv = threadIdx.x >> 6, lane = threadIdx.x & 63;
    const size_t row = (size_t)blockIdx.x * 4 + wv;
    const float* r = in + row * 768;
    float v[12], s = 0.f, sq = 0.f;
    #pragma unroll
    for (int j = 0; j < 12; ++j) {
        float t = r[j * 64 + lane];
        v[j] = t; s += t; sq += t * t;
    }
    #pragma unroll
    for (int off = 1; off < 64; off <<= 1) {
        s += __shfl_xor(s, off, 64);
        sq += __shfl_xor(sq, off, 64);
    }
    const float mu = s * (1.f / 768.f);
    const float var = sq * (1.f / 768.f) - mu * mu;
    const float rs = rsqrtf(var + 1e-6f);
    #pragma unroll
    for (int j = 0; j < 12; ++j) {
        int col = j * 64 + lane;
        float y = (v[j] - mu) * rs * g[col] + be[col];
        if (isb) ((bf16*)out)[row * 768 + col] = (bf16)y;
        else     ((float*)out)[row * 768 + col] = y;
    }
}

// ---------------- host ----------------
extern "C" void kernel_launch(void* const* d_in, const int* in_sizes, int n_in,
                              void* d_out, int out_size, void* d_ws, size_t ws_size,
                              hipStream_t stream)
{
    const void* src  = d_in[0];
    const void* Wq   = d_in[1];
    const void* bq   = d_in[2];
    const void* Wk   = d_in[3];
    const void* bk   = d_in[4];
    const void* Wv   = d_in[5];
    const void* bv   = d_in[6];
    const void* W1   = d_in[7];
    const void* b1   = d_in[8];
    const void* W2   = d_in[9];
    const void* b2   = d_in[10];
    const void* ln2g = d_in[11];
    const void* ln2b = d_in[12];
    const void* lnfg = d_in[13];
    const void* lnfb = d_in[14];

    // Workspace layout — TOTAL ~72.5 MB
    char* ws = (char*)d_ws;
    float* x     = (float*)(ws);                  // [8192][768] fp32 residual  25,165,824 B
    bf16*  sh    = (bf16*) (ws + 25165824);       // 37,748,736 B: qkv [8192][2304] / h1-half [4096][3072]
    bf16*  wT    = (bf16*) (ws + 62914560);       // wqkvT [2304][768] or w1T [3072][768]  (4,718,592 B)
    bf16*  w2T   = (bf16*) (ws + 67633152);       // [768][3072]  4,718,592 B
    float* qbias = (float*)(ws + 72351744);       // [4][2304] fp32   36,864 B
    float* b1c   = (float*)(ws + 72388608);       // [4][3072]        49,152 B
    float* b2c   = (float*)(ws + 72437760);       // [4][768]         12,288 B
    float* ln2gc = (float*)(ws + 72450048);       // [4][768]         12,288 B
    float* ln2bc = (float*)(ws + 72462336);       // [4][768]         12,288 B
    float* lnfgc = (float*)(ws + 72474624);       // [768]             3,072 B
    float* lnfbc = (float*)(ws + 72477696);       // [768]             3,072 B
    int*   flag  = (int*)  (ws + 72480768);       // dtype flag
                                                  // end: 72,480,772 B

    sniff_kernel<<<1, 256, 0, stream>>>((const unsigned short*)src, flag);

    cvt32_kernel<<<1024, 256, 0, stream>>>(src, x, 8192 * 768, flag);
    concat_bias_kernel<<<36, 256, 0, stream>>>(bq, bk, bv, qbias, flag);
    cvt32_kernel<<<48, 256, 0, stream>>>(b1, b1c, 4 * 3072, flag);
    cvt32_kernel<<<12, 256, 0, stream>>>(b2, b2c, 4 * 768, flag);
    cvt32_kernel<<<12, 256, 0, stream>>>(ln2g, ln2gc, 4 * 768, flag);
    cvt32_kernel<<<12, 256, 0, stream>>>(ln2b, ln2bc, 4 * 768, flag);
    cvt32_kernel<<<3, 256, 0, stream>>>(lnfg, lnfgc, 768, flag);
    cvt32_kernel<<<3, 256, 0, stream>>>(lnfb, lnfbc, 768, flag);

    for (int i = 0; i < 4; ++i) {
        const size_t woQ = (size_t)i * 768 * 768;
        const size_t wo1 = (size_t)i * 768 * 3072;
        const size_t wo2 = (size_t)i * 3072 * 768;

        transpose_kernel<<<dim3(12, 12), 256, 0, stream>>>(Wq, woQ, wT,              768, 768, flag);
        transpose_kernel<<<dim3(12, 12), 256, 0, stream>>>(Wk, woQ, wT + 768 * 768,  768, 768, flag);
        transpose_kernel<<<dim3(12, 12), 256, 0, stream>>>(Wv, woQ, wT + 1536 * 768, 768, 768, flag);

        // QKV: sh = bf16((x @ WqkvT) + bias), Q cols scaled 1/8
        gemm_kernel<<<dim3(18, 64), 256, 0, stream>>>(x, 1, wT, qbias + i * 2304,
                                                      sh, nullptr, 8192, 2304, 768, 0, 768);
        attn_kernel<<<dim3(32, 12, 2), 256, 0, stream>>>(sh, x);

        transpose_kernel<<<dim3(48, 12), 256, 0, stream>>>(W1, wo1, wT,  768, 3072, flag);
        transpose_kernel<<<dim3(12, 48), 256, 0, stream>>>(W2, wo2, w2T, 3072, 768, flag);

        // FFN in two M-halves (h1-half 4096x3072 bf16 fits sh)
        for (int half = 0; half < 2; ++half) {
            float* xh = x + (size_t)half * 4096 * 768;
            gemm_kernel<<<dim3(24, 32), 256, 0, stream>>>(xh, 1, wT, b1c + i * 3072,
                                                          sh, nullptr, 4096, 3072, 768, 1, 0);
            gemm_kernel<<<dim3(6, 32), 256, 0, stream>>>(sh, 0, w2T, b2c + i * 768,
                                                         nullptr, xh, 4096, 768, 3072, 2, 0);
        }
        ln_kernel<<<2048, 256, 0, stream>>>(x, ln2gc + i * 768, ln2bc + i * 768, x);
    }
    ln_final_kernel<<<2048, 256, 0, stream>>>(x, lnfgc, lnfbc, d_out, flag);
}

// Round 5
// 1487.723 us; speedup vs baseline: 1.8822x; 1.8822x over previous
//
#include <hip/hip_runtime.h>

typedef __bf16 bf16;
typedef __bf16 bf16x8 __attribute__((ext_vector_type(8)));
typedef float floatx4 __attribute__((ext_vector_type(4)));

#define MFMA16(a, b, c) __builtin_amdgcn_mfma_f32_16x16x32_bf16((a), (b), (c), 0, 0, 0)
#define NEG_SENT -30000.0f

// async global->LDS, 16B/lane; LDS dest = wave-uniform base + lane*16
#define GLOAD_LDS16(gp, lp)                                                              \
    __builtin_amdgcn_global_load_lds((const __attribute__((address_space(1))) void*)(gp), \
                                     (__attribute__((address_space(3))) void*)(lp), 16, 0, 0)

// B=2, S=4096, D=768, H=12, DH=64, W=128, nc=32, DFF=3072, L=4

// flag: 1 = inputs bf16, 0 = inputs fp32 (measured: this harness = fp32)
__device__ __forceinline__ float ldin(const void* p, size_t i, int isb)
{
    return isb ? (float)((const bf16*)p)[i] : ((const float*)p)[i];
}

__global__ __launch_bounds__(256) void sniff_kernel(const unsigned short* __restrict__ s,
                                                    int* __restrict__ flag)
{
    __shared__ int cnt;
    if (threadIdx.x == 0) cnt = 0;
    __syncthreads();
    int good = 0;
    #pragma unroll
    for (int t = 0; t < 16; ++t) {
        unsigned short h = s[threadIdx.x * 16 + t];
        int e = (h >> 7) & 0xFF;
        if (h == 0 || (e >= 96 && e <= 158)) good++;
    }
    atomicAdd(&cnt, good);
    __syncthreads();
    if (threadIdx.x == 0) *flag = (cnt >= 3700) ? 1 : 0;
}

// src -> x (fp32) + xb (bf16 mirror, optional)
__global__ __launch_bounds__(256) void cvt_src_kernel(const void* __restrict__ s,
                                                      float* __restrict__ x,
                                                      bf16* __restrict__ xb, int n,
                                                      const int* __restrict__ flag)
{
    const int isb = *flag;
    const int stride = gridDim.x * 256;
    if (xb) {
        for (int i = blockIdx.x * 256 + threadIdx.x; i < n; i += stride) {
            float v = ldin(s, i, isb);
            x[i] = v; xb[i] = (bf16)v;
        }
    } else {
        for (int i = blockIdx.x * 256 + threadIdx.x; i < n; i += stride)
            x[i] = ldin(s, i, isb);
    }
}

// all small params -> fp32 canon block (qbias|b1|b2|ln2g|ln2b|lnfg|lnfb), 32256 elems
__global__ __launch_bounds__(256) void prep_kernel(
    const void* __restrict__ bq, const void* __restrict__ bk, const void* __restrict__ bv,
    const void* __restrict__ b1, const void* __restrict__ b2,
    const void* __restrict__ ln2g, const void* __restrict__ ln2b,
    const void* __restrict__ lnfg, const void* __restrict__ lnfb,
    float* __restrict__ dst, const int* __restrict__ flag)
{
    const int isb = *flag;
    int i = blockIdx.x * 256 + threadIdx.x;
    if (i < 9216) {
        int l = i / 2304, c = i % 2304;
        float v = (c < 768)  ? ldin(bq, l * 768 + c, isb)
                : (c < 1536) ? ldin(bk, l * 768 + c - 768, isb)
                             : ldin(bv, l * 768 + c - 1536, isb);
        dst[i] = v; return;
    }
    i -= 9216;
    if (i < 12288) { dst[9216 + i]  = ldin(b1, i, isb);   return; } i -= 12288;
    if (i < 3072)  { dst[21504 + i] = ldin(b2, i, isb);   return; } i -= 3072;
    if (i < 3072)  { dst[24576 + i] = ldin(ln2g, i, isb); return; } i -= 3072;
    if (i < 3072)  { dst[27648 + i] = ldin(ln2b, i, isb); return; } i -= 3072;
    if (i < 768)   { dst[30720 + i] = ldin(lnfg, i, isb); return; } i -= 768;
    if (i < 768)   { dst[31488 + i] = ldin(lnfb, i, isb); return; }
}

// generic transpose: src[eoff + K][N] -> dst[N][K] (bf16)
__global__ __launch_bounds__(256) void transpose_kernel(const void* __restrict__ src,
                                                        size_t eoff, bf16* __restrict__ dst,
                                                        int K, int N,
                                                        const int* __restrict__ flag)
{
    __shared__ bf16 tile[64][65];
    const int isb = *flag;
    const int n0 = blockIdx.x * 64, k0 = blockIdx.y * 64;
    const int tid = threadIdx.x;
    #pragma unroll
    for (int it = 0; it < 16; ++it) {
        int idx = it * 256 + tid;
        int r = idx >> 6, c = idx & 63;
        tile[r][c] = (bf16)ldin(src, eoff + (size_t)(k0 + r) * N + (n0 + c), isb);
    }
    __syncthreads();
    #pragma unroll
    for (int it = 0; it < 16; ++it) {
        int idx = it * 256 + tid;
        int r = idx >> 6, c = idx & 63;
        dst[(size_t)(n0 + r) * K + (k0 + c)] = tile[c][r];
    }
}

// batched Wq/Wk/Wv transpose (z = 0/1/2), 768x768 each
__global__ __launch_bounds__(256) void transpose3_kernel(const void* __restrict__ Wq,
                                                         const void* __restrict__ Wk,
                                                         const void* __restrict__ Wv,
                                                         size_t eoff, bf16* __restrict__ dst,
                                                         const int* __restrict__ flag)
{
    __shared__ bf16 tile[64][65];
    const int isb = *flag;
    const void* src = (blockIdx.z == 0) ? Wq : (blockIdx.z == 1) ? Wk : Wv;
    bf16* d = dst + (size_t)blockIdx.z * 768 * 768;
    const int n0 = blockIdx.x * 64, k0 = blockIdx.y * 64;
    const int tid = threadIdx.x;
    #pragma unroll
    for (int it = 0; it < 16; ++it) {
        int idx = it * 256 + tid;
        int r = idx >> 6, c = idx & 63;
        tile[r][c] = (bf16)ldin(src, eoff + (size_t)(k0 + r) * 768 + (n0 + c), isb);
    }
    __syncthreads();
    #pragma unroll
    for (int it = 0; it < 16; ++it) {
        int idx = it * 256 + tid;
        int r = idx >> 6, c = idx & 63;
        d[(size_t)(n0 + r) * 768 + (k0 + c)] = tile[c][r];
    }
}

// ---------------- GEMM: C = A[M][K] @ Bt[N][K]^T + bias ----------------
// Tile: BM(=AM*32) x 128, BK=64, 4 waves (2x2), m97-style global_load_lds staging.
// mode 0: outb = bf16((acc+bias)*(col<scale_cols?0.125:1))
// mode 1: outb = bf16(relu(acc+bias))
// mode 2: outf += acc + bias   (fp32 residual RMW)
template<int AM>
__global__ __launch_bounds__(256, 4) void gemm_kernel(
    const void* __restrict__ A, int a_f32, const bf16* __restrict__ Bt,
    const float* __restrict__ bias,
    bf16* __restrict__ outb, float* __restrict__ outf,
    int M, int N, int K, int mode, int scale_cols)
{
    constexpr int BM = AM * 32;
    constexpr int BN = 128;
    __shared__ __align__(16) bf16 smem[(BM + BN) * 64];  // unpadded: required by global_load_lds
    bf16* As = smem;             // [BM][64]
    bf16* Bs = smem + BM * 64;   // [BN][64]

    const int tid = threadIdx.x;
    const int m0 = blockIdx.y * BM, n0 = blockIdx.x * BN;
    const int lane = tid & 63, wave = tid >> 6;
    const int wr = (wave >> 1) * (AM * 16), wc = (wave & 1) * 64;
    const int l16 = lane & 15, quad = lane >> 4;
    const int lrow = lane >> 3, lcol = (lane & 7) * 8;

    floatx4 acc[AM][4];
    #pragma unroll
    for (int i = 0; i < AM; ++i)
        #pragma unroll
        for (int j = 0; j < 4; ++j)
            #pragma unroll
            for (int r = 0; r < 4; ++r) acc[i][j][r] = 0.f;

    for (int k0 = 0; k0 < K; k0 += 64) {
        if (a_f32) {
            const float* Af = (const float*)A;
            #pragma unroll
            for (int it = 0; it < AM; ++it) {           // BM*64 elems, 256 thr, 8/thr
                int chunk = it * 256 + tid;
                int row = chunk >> 3, c8 = (chunk & 7) * 8;
                size_t off = (size_t)(m0 + row) * K + k0 + c8;
                float4 f0 = *(const float4*)&Af[off];
                float4 f1 = *(const float4*)&Af[off + 4];
                bf16x8 v;
                v[0] = (bf16)f0.x; v[1] = (bf16)f0.y; v[2] = (bf16)f0.z; v[3] = (bf16)f0.w;
                v[4] = (bf16)f1.x; v[5] = (bf16)f1.y; v[6] = (bf16)f1.z; v[7] = (bf16)f1.w;
                *(bf16x8*)&As[row * 64 + c8] = v;
            }
            for (int s = wave; s < BN / 8; s += 4) {
                const bf16* gp = Bt + (size_t)(n0 + s * 8 + lrow) * K + k0 + lcol;
                GLOAD_LDS16(gp, Bs + s * 512);
            }
        } else {
            const bf16* Ab = (const bf16*)A;
            for (int s = wave; s < (BM + BN) / 8; s += 4) {  // 1024B per wave-instr
                const bf16* gp; bf16* lp;
                if (s < BM / 8) {
                    gp = Ab + (size_t)(m0 + s * 8 + lrow) * K + k0 + lcol;
                    lp = As + s * 512;
                } else {
                    int s2 = s - BM / 8;
                    gp = Bt + (size_t)(n0 + s2 * 8 + lrow) * K + k0 + lcol;
                    lp = Bs + s2 * 512;
                }
                GLOAD_LDS16(gp, lp);
            }
        }
        __syncthreads();
        #pragma unroll
        for (int kk = 0; kk < 64; kk += 32) {
            bf16x8 af[AM], bv[4];
            #pragma unroll
            for (int i = 0; i < AM; ++i) af[i] = *(const bf16x8*)&As[(wr + i * 16 + l16) * 64 + kk + quad * 8];
            #pragma unroll
            for (int j = 0; j < 4; ++j)  bv[j] = *(const bf16x8*)&Bs[(wc + j * 16 + l16) * 64 + kk + quad * 8];
            #pragma unroll
            for (int i = 0; i < AM; ++i)
                #pragma unroll
                for (int j = 0; j < 4; ++j)
                    acc[i][j] = MFMA16(af[i], bv[j], acc[i][j]);
        }
        __syncthreads();
    }

    #pragma unroll
    for (int j = 0; j < 4; ++j) {
        int col = n0 + wc + j * 16 + l16;
        float bs = bias[col];
        float alpha = (col < scale_cols) ? 0.125f : 1.0f;
        #pragma unroll
        for (int i = 0; i < AM; ++i) {
            #pragma unroll
            for (int r = 0; r < 4; ++r) {
                int row = m0 + wr + i * 16 + quad * 4 + r;
                size_t idx = (size_t)row * N + col;
                float v = (acc[i][j][r] + bs) * alpha;
                if (mode == 0)      outb[idx] = (bf16)v;
                else if (mode == 1) outb[idx] = (bf16)fmaxf(v, 0.f);
                else                outf[idx] += v;
            }
        }
    }
}

// ---------------- banded flash attention: x += attn, xb = bf16(x) ----------------
// qkv: [B*S][2304] bf16 (Q/8 | K | V). grid (nc=32, H=12, B=2), 4 waves.
__global__ __launch_bounds__(256, 2) void attn_kernel(const bf16* __restrict__ qkv,
                                                      float* __restrict__ x,
                                                      bf16* __restrict__ xb)
{
    __shared__ __align__(16) bf16 Ks[128 * 64];   // [key][d] unpadded (global_load_lds)
    __shared__ __align__(16) bf16 Vt[64 * 136];   // [d][key] B-operand layout
    __shared__ __align__(16) bf16 Ps[128 * 136];  // [q][key] A-operand layout

    const int c = blockIdx.x, h = blockIdx.y, b = blockIdx.z;
    const int tid = threadIdx.x;
    const int lane = tid & 63, w = tid >> 6;
    const int l16 = lane & 15, quad = lane >> 4;
    const int lrow = lane >> 3, lcol = (lane & 7) * 8;
    const size_t rowbase = (size_t)(b * 4096 + c * 128);

    // Q fragments live in registers (no LDS round-trip)
    bf16x8 aq[2][2];
    #pragma unroll
    for (int i = 0; i < 2; ++i)
        #pragma unroll
        for (int kh = 0; kh < 2; ++kh)
            aq[i][kh] = *(const bf16x8*)&qkv[(rowbase + w * 32 + i * 16 + l16) * 2304 + h * 64 + kh * 32 + quad * 8];

    floatx4 o[2][4], mr[2], lr[2];
    #pragma unroll
    for (int i = 0; i < 2; ++i) {
        #pragma unroll
        for (int r = 0; r < 4; ++r) { mr[i][r] = NEG_SENT; lr[i][r] = 0.f; }
        #pragma unroll
        for (int tv = 0; tv < 4; ++tv)
            #pragma unroll
            for (int r = 0; r < 4; ++r) o[i][tv][r] = 0.f;
    }

    const int t0 = (c == 0) ? 1 : 0;
    const int t1 = (c == 31) ? 1 : 2;
    for (int t = t0; t <= t1; ++t) {
        const size_t kb = (size_t)(b * 4096 + c * 128 + (t - 1) * 128);
        __syncthreads();  // prev iteration's readers done
        for (int s = w; s < 16; s += 4) {
            const bf16* gp = &qkv[(kb + s * 8 + lrow) * 2304 + 768 + h * 64 + lcol];
            GLOAD_LDS16(gp, Ks + s * 512);
        }
        for (int idx = tid; idx < 8192; idx += 256) {
            int key = idx >> 6, dh = idx & 63;
            Vt[dh * 136 + key] = qkv[(kb + key) * 2304 + 1536 + h * 64 + dh];
        }
        __syncthreads();

        // S = Q K^T
        floatx4 st[2][8];
        #pragma unroll
        for (int i = 0; i < 2; ++i)
            #pragma unroll
            for (int j = 0; j < 8; ++j)
                #pragma unroll
                for (int r = 0; r < 4; ++r) st[i][j][r] = 0.f;
        #pragma unroll
        for (int kh = 0; kh < 2; ++kh) {
            #pragma unroll
            for (int j = 0; j < 8; ++j) {
                bf16x8 bk = *(const bf16x8*)&Ks[(j * 16 + l16) * 64 + kh * 32 + quad * 8];
                st[0][j] = MFMA16(aq[0][kh], bk, st[0][j]);
                st[1][j] = MFMA16(aq[1][kh], bk, st[1][j]);
            }
        }
        if (t != 1) {
            #pragma unroll
            for (int i = 0; i < 2; ++i)
                #pragma unroll
                for (int j = 0; j < 8; ++j)
                    #pragma unroll
                    for (int r = 0; r < 4; ++r) {
                        int qi = w * 32 + i * 16 + quad * 4 + r;
                        int ki = j * 16 + l16;
                        bool valid = (t == 0) ? (ki >= qi) : (ki <= qi);
                        if (!valid) st[i][j][r] = NEG_SENT;
                    }
        }
        // online softmax (rows across a quad's 16 lanes)
        #pragma unroll
        for (int i = 0; i < 2; ++i) {
            floatx4 mx = st[i][0];
            #pragma unroll
            for (int j = 1; j < 8; ++j)
                #pragma unroll
                for (int r = 0; r < 4; ++r) mx[r] = fmaxf(mx[r], st[i][j][r]);
            #pragma unroll
            for (int r = 0; r < 4; ++r) {
                float v = mx[r];
                #pragma unroll
                for (int off = 1; off < 16; off <<= 1) v = fmaxf(v, __shfl_xor(v, off, 64));
                mx[r] = v;
            }
            floatx4 scale;
            #pragma unroll
            for (int r = 0; r < 4; ++r) {
                float mnew = fmaxf(mr[i][r], mx[r]);
                scale[r] = __expf(mr[i][r] - mnew);
                mr[i][r] = mnew;
            }
            floatx4 psum;
            #pragma unroll
            for (int r = 0; r < 4; ++r) psum[r] = 0.f;
            #pragma unroll
            for (int j = 0; j < 8; ++j)
                #pragma unroll
                for (int r = 0; r < 4; ++r) {
                    float p = __expf(st[i][j][r] - mr[i][r]);
                    psum[r] += p;
                    Ps[(w * 32 + i * 16 + quad * 4 + r) * 136 + j * 16 + l16] = (bf16)p;
                }
            #pragma unroll
            for (int r = 0; r < 4; ++r) {
                float v = psum[r];
                #pragma unroll
                for (int off = 1; off < 16; off <<= 1) v += __shfl_xor(v, off, 64);
                lr[i][r] = lr[i][r] * scale[r] + v;
            }
            #pragma unroll
            for (int tv = 0; tv < 4; ++tv)
                #pragma unroll
                for (int r = 0; r < 4; ++r) o[i][tv][r] *= scale[r];
        }
        __syncthreads();  // publish Ps
        // O += P V
        #pragma unroll
        for (int kk = 0; kk < 128; kk += 32) {
            bf16x8 ap0 = *(const bf16x8*)&Ps[(w * 32 + l16) * 136 + kk + quad * 8];
            bf16x8 ap1 = *(const bf16x8*)&Ps[(w * 32 + 16 + l16) * 136 + kk + quad * 8];
            #pragma unroll
            for (int tv = 0; tv < 4; ++tv) {
                bf16x8 bv = *(const bf16x8*)&Vt[(tv * 16 + l16) * 136 + kk + quad * 8];
                o[0][tv] = MFMA16(ap0, bv, o[0][tv]);
                o[1][tv] = MFMA16(ap1, bv, o[1][tv]);
            }
        }
    }

    // epilogue: normalize, residual add (disjoint cols per h), mirror to xb
    #pragma unroll
    for (int i = 0; i < 2; ++i)
        #pragma unroll
        for (int r = 0; r < 4; ++r) {
            int srow = w * 32 + i * 16 + quad * 4 + r;
            size_t base = (rowbase + srow) * 768 + h * 64;
            float inv = 1.f / lr[i][r];
            #pragma unroll
            for (int tv = 0; tv < 4; ++tv) {
                size_t idx = base + tv * 16 + l16;
                float val = x[idx] + o[i][tv][r] * inv;
                x[idx] = val;
                if (xb) xb[idx] = (bf16)val;
            }
        }
}

// ---------------- LayerNorm D=768, fp32 residual, optional bf16 mirror ----------------
__global__ __launch_bounds__(256) void ln_kernel(const float* in,
                                                 const float* __restrict__ g,
                                                 const float* __restrict__ be,
                                                 float* out, bf16* outb)
{
    const int wv = threadIdx.x >> 6, lane = threadIdx.x & 63;
    const size_t row = (size_t)blockIdx.x * 4 + wv;
    const float* r = in + row * 768;
    float v[12], s = 0.f, sq = 0.f;
    #pragma unroll
    for (int j = 0; j < 12; ++j) {
        float t = r[j * 64 + lane];
        v[j] = t; s += t; sq += t * t;
    }
    #pragma unroll
    for (int off = 1; off < 64; off <<= 1) {
        s += __shfl_xor(s, off, 64);
        sq += __shfl_xor(sq, off, 64);
    }
    const float mu = s * (1.f / 768.f);
    const float var = sq * (1.f / 768.f) - mu * mu;
    const float rs = rsqrtf(var + 1e-6f);
    #pragma unroll
    for (int j = 0; j < 12; ++j) {
        int col = j * 64 + lane;
        float y = (v[j] - mu) * rs * g[col] + be[col];
        out[row * 768 + col] = y;
        if (outb) outb[row * 768 + col] = (bf16)y;
    }
}

// final LN -> d_out in flag-selected dtype
__global__ __launch_bounds__(256) void ln_final_kernel(const float* __restrict__ in,
                                                       const float* __restrict__ g,
                                                       const float* __restrict__ be,
                                                       void* __restrict__ out,
                                                       const int* __restrict__ flag)
{
    const int isb = *flag;
    const int wv = threadIdx.x >> 6, lane = threadIdx.x & 63;
    const size_t row = (size_t)blockIdx.x * 4 + wv;
    const float* r = in + row * 768;
    float v[12], s = 0.f, sq = 0.f;
    #pragma unroll
    for (int j = 0; j < 12; ++j) {
        float t = r[j * 64 + lane];
        v[j] = t; s += t; sq += t * t;
    }
    #pragma unroll
    for (int off = 1; off < 64; off <<= 1) {
        s += __shfl_xor(s, off, 64);
        sq += __shfl_xor(sq, off, 64);
    }
    const float mu = s * (1.f / 768.f);
    const float var = sq * (1.f / 768.f) - mu * mu;
    const float rs = rsqrtf(var + 1e-6f);
    #pragma unroll
    for (int j = 0; j < 12; ++j) {
        int col = j * 64 + lane;
        float y = (v[j] - mu) * rs * g[col] + be[col];
        if (isb) ((bf16*)out)[row * 768 + col] = (bf16)y;
        else     ((float*)out)[row * 768 + col] = y;
    }
}

// ---------------- host ----------------
extern "C" void kernel_launch(void* const* d_in, const int* in_sizes, int n_in,
                              void* d_out, int out_size, void* d_ws, size_t ws_size,
                              hipStream_t stream)
{
    const void* src  = d_in[0];
    const void* Wq   = d_in[1];
    const void* bq   = d_in[2];
    const void* Wk   = d_in[3];
    const void* bk   = d_in[4];
    const void* Wv   = d_in[5];
    const void* bv   = d_in[6];
    const void* W1   = d_in[7];
    const void* b1   = d_in[8];
    const void* W2   = d_in[9];
    const void* b2   = d_in[10];
    const void* ln2g = d_in[11];
    const void* ln2b = d_in[12];
    const void* lnfg = d_in[13];
    const void* lnfb = d_in[14];

    const size_t SZ_X   = 8192ull * 768 * 4;   // 25,165,824
    const size_t SZ_XB  = 8192ull * 768 * 2;   // 12,582,912
    const size_t SZ_QKV = 8192ull * 2304 * 2;  // 37,748,736
    const size_t SZ_H1F = 8192ull * 3072 * 2;  // 50,331,648
    const size_t SZ_W1  = 3072ull * 768 * 2;   //  4,718,592 (also holds qkvT 3.5MB)
    const size_t SZ_W2  = 4718592;
    const size_t SMALL  = 131072;
    const size_t needA = SZ_X + SZ_XB + SZ_H1F + SZ_W1 + SZ_W2 + SMALL;  // 97,648,640
    const size_t needB = SZ_X + SZ_XB + SZ_QKV + SZ_W1 + SZ_W2 + SMALL; // 85,065,728
    // layout 2: full-M FFN + xb; 1: half-M FFN + xb; 0: half-M, no xb (A=fp32 path)
    const int lay = (ws_size >= needA) ? 2 : (ws_size >= needB) ? 1 : 0;

    char* p = (char*)d_ws;
    float* x = (float*)p;  p += SZ_X;
    bf16* xb = nullptr;
    if (lay) { xb = (bf16*)p; p += SZ_XB; }
    bf16* sh  = (bf16*)p;  p += (lay == 2) ? SZ_H1F : SZ_QKV;
    bf16* wT  = (bf16*)p;  p += SZ_W1;
    bf16* w2T = (bf16*)p;  p += SZ_W2;
    float* sm = (float*)p;
    float* qbias = sm;          float* b1c = sm + 9216;   float* b2c = sm + 21504;
    float* ln2gc = sm + 24576;  float* ln2bc = sm + 27648;
    float* lnfgc = sm + 30720;  float* lnfbc = sm + 31488;
    int* flag = (int*)(sm + 32256);

    sniff_kernel<<<1, 256, 0, stream>>>((const unsigned short*)src, flag);
    cvt_src_kernel<<<1024, 256, 0, stream>>>(src, x, xb, 8192 * 768, flag);
    prep_kernel<<<126, 256, 0, stream>>>(bq, bk, bv, b1, b2, ln2g, ln2b, lnfg, lnfb, sm, flag);

    for (int i = 0; i < 4; ++i) {
        const size_t woQ = (size_t)i * 768 * 768;
        const size_t wo1 = (size_t)i * 768 * 3072;
        const size_t wo2 = (size_t)i * 3072 * 768;

        transpose3_kernel<<<dim3(12, 12, 3), 256, 0, stream>>>(Wq, Wk, Wv, woQ, wT, flag);

        if (lay)
            gemm_kernel<4><<<dim3(18, 64), 256, 0, stream>>>(xb, 0, wT, qbias + i * 2304,
                                                             sh, nullptr, 8192, 2304, 768, 0, 768);
        else
            gemm_kernel<4><<<dim3(18, 64), 256, 0, stream>>>(x, 1, wT, qbias + i * 2304,
                                                             sh, nullptr, 8192, 2304, 768, 0, 768);
        attn_kernel<<<dim3(32, 12, 2), 256, 0, stream>>>(sh, x, xb);

        transpose_kernel<<<dim3(48, 12), 256, 0, stream>>>(W1, wo1, wT, 768, 3072, flag);
        transpose_kernel<<<dim3(12, 48), 256, 0, stream>>>(W2, wo2, w2T, 3072, 768, flag);

        if (lay == 2) {
            gemm_kernel<4><<<dim3(24, 64), 256, 0, stream>>>(xb, 0, wT, b1c + i * 3072,
                                                             sh, nullptr, 8192, 3072, 768, 1, 0);
            gemm_kernel<2><<<dim3(6, 128), 256, 0, stream>>>(sh, 0, w2T, b2c + i * 768,
                                                             nullptr, x, 8192, 768, 3072, 2, 0);
        } else {
            for (int half = 0; half < 2; ++half) {
                float* xh = x + (size_t)half * 4096 * 768;
                const void* A1 = lay ? (const void*)(xb + (size_t)half * 4096 * 768) : (const void*)xh;
                gemm_kernel<4><<<dim3(24, 32), 256, 0, stream>>>(A1, lay ? 0 : 1, wT, b1c + i * 3072,
                                                                 sh, nullptr, 4096, 3072, 768, 1, 0);
                gemm_kernel<2><<<dim3(6, 64), 256, 0, stream>>>(sh, 0, w2T, b2c + i * 768,
                                                                nullptr, xh, 4096, 768, 3072, 2, 0);
            }
        }
        ln_kernel<<<2048, 256, 0, stream>>>(x, ln2gc + i * 768, ln2bc + i * 768, x, xb);
    }
    ln_final_kernel<<<2048, 256, 0, stream>>>(x, lnfgc, lnfbc, d_out, flag);
}

// Round 6
// 1387.027 us; speedup vs baseline: 2.0188x; 1.0726x over previous
//
#include <hip/hip_runtime.h>

typedef __bf16 bf16;
typedef __bf16 bf16x8 __attribute__((ext_vector_type(8)));
typedef float floatx4 __attribute__((ext_vector_type(4)));

#define MFMA16(a, b, c) __builtin_amdgcn_mfma_f32_16x16x32_bf16((a), (b), (c), 0, 0, 0)
#define NEG_SENT -30000.0f

// async global->LDS, 16B/lane; LDS dest = wave-uniform base + lane*16
#define GLOAD_LDS16(gp, lp)                                                              \
    __builtin_amdgcn_global_load_lds((const __attribute__((address_space(1))) void*)(gp), \
                                     (__attribute__((address_space(3))) void*)(lp), 16, 0, 0)

// B=2, S=4096, D=768, H=12, DH=64, W=128, nc=32, DFF=3072, L=4

__device__ __forceinline__ void atomAddF(float* p, float v) { unsafeAtomicAdd(p, v); }

// flag: 1 = inputs bf16, 0 = inputs fp32 (measured round 3/4: this harness = fp32)
__device__ __forceinline__ float ldin(const void* p, size_t i, int isb)
{
    return isb ? (float)((const bf16*)p)[i] : ((const float*)p)[i];
}

__global__ __launch_bounds__(256) void sniff_kernel(const unsigned short* __restrict__ s,
                                                    int* __restrict__ flag)
{
    __shared__ int cnt;
    if (threadIdx.x == 0) cnt = 0;
    __syncthreads();
    int good = 0;
    #pragma unroll
    for (int t = 0; t < 16; ++t) {
        unsigned short h = s[threadIdx.x * 16 + t];
        int e = (h >> 7) & 0xFF;
        if (h == 0 || (e >= 96 && e <= 158)) good++;
    }
    atomicAdd(&cnt, good);
    __syncthreads();
    if (threadIdx.x == 0) *flag = (cnt >= 3700) ? 1 : 0;
}

// src -> x (fp32) + xb (bf16 mirror, optional)
__global__ __launch_bounds__(256) void cvt_src_kernel(const void* __restrict__ s,
                                                      float* __restrict__ x,
                                                      bf16* __restrict__ xb, int n,
                                                      const int* __restrict__ flag)
{
    const int isb = *flag;
    const int stride = gridDim.x * 256;
    if (xb) {
        for (int i = blockIdx.x * 256 + threadIdx.x; i < n; i += stride) {
            float v = ldin(s, i, isb);
            x[i] = v; xb[i] = (bf16)v;
        }
    } else {
        for (int i = blockIdx.x * 256 + threadIdx.x; i < n; i += stride)
            x[i] = ldin(s, i, isb);
    }
}

// all small params -> fp32 canon block (qbias|b1|b2|ln2g|ln2b|lnfg|lnfb)
__global__ __launch_bounds__(256) void prep_kernel(
    const void* __restrict__ bq, const void* __restrict__ bk, const void* __restrict__ bv,
    const void* __restrict__ b1, const void* __restrict__ b2,
    const void* __restrict__ ln2g, const void* __restrict__ ln2b,
    const void* __restrict__ lnfg, const void* __restrict__ lnfb,
    float* __restrict__ dst, const int* __restrict__ flag)
{
    const int isb = *flag;
    int i = blockIdx.x * 256 + threadIdx.x;
    if (i < 9216) {
        int l = i / 2304, c = i % 2304;
        float v = (c < 768)  ? ldin(bq, l * 768 + c, isb)
                : (c < 1536) ? ldin(bk, l * 768 + c - 768, isb)
                             : ldin(bv, l * 768 + c - 1536, isb);
        dst[i] = v; return;
    }
    i -= 9216;
    if (i < 12288) { dst[9216 + i]  = ldin(b1, i, isb);   return; } i -= 12288;
    if (i < 3072)  { dst[21504 + i] = ldin(b2, i, isb);   return; } i -= 3072;
    if (i < 3072)  { dst[24576 + i] = ldin(ln2g, i, isb); return; } i -= 3072;
    if (i < 3072)  { dst[27648 + i] = ldin(ln2b, i, isb); return; } i -= 3072;
    if (i < 768)   { dst[30720 + i] = ldin(lnfg, i, isb); return; } i -= 768;
    if (i < 768)   { dst[31488 + i] = ldin(lnfb, i, isb); return; }
}

// batched Wq/Wk/Wv transpose (z = 0/1/2), 768x768 each -> dst[N][K]
__global__ __launch_bounds__(256) void transpose3_kernel(const void* __restrict__ Wq,
                                                         const void* __restrict__ Wk,
                                                         const void* __restrict__ Wv,
                                                         size_t eoff, bf16* __restrict__ dst,
                                                         const int* __restrict__ flag)
{
    __shared__ bf16 tile[64][65];
    const int isb = *flag;
    const void* src = (blockIdx.z == 0) ? Wq : (blockIdx.z == 1) ? Wk : Wv;
    bf16* d = dst + (size_t)blockIdx.z * 768 * 768;
    const int n0 = blockIdx.x * 64, k0 = blockIdx.y * 64;
    const int tid = threadIdx.x;
    #pragma unroll
    for (int it = 0; it < 16; ++it) {
        int idx = it * 256 + tid;
        int r = idx >> 6, c = idx & 63;
        tile[r][c] = (bf16)ldin(src, eoff + (size_t)(k0 + r) * 768 + (n0 + c), isb);
    }
    __syncthreads();
    #pragma unroll
    for (int it = 0; it < 16; ++it) {
        int idx = it * 256 + tid;
        int r = idx >> 6, c = idx & 63;
        d[(size_t)(n0 + r) * 768 + (k0 + c)] = tile[c][r];
    }
}

// merged W1 (z=0: 768x3072) + W2 (z=1: 3072x768) transpose
__global__ __launch_bounds__(256) void transpose12_kernel(const void* __restrict__ W1,
                                                          size_t eoff1, bf16* __restrict__ d1,
                                                          const void* __restrict__ W2,
                                                          size_t eoff2, bf16* __restrict__ d2,
                                                          const int* __restrict__ flag)
{
    __shared__ bf16 tile[64][65];
    const int isb = *flag;
    const int z = blockIdx.z;
    const void* src = z ? W2 : W1;
    const size_t eoff = z ? eoff2 : eoff1;
    bf16* d = z ? d2 : d1;
    const int K = z ? 3072 : 768, N = z ? 768 : 3072;
    const int n0 = (z ? blockIdx.y : blockIdx.x) * 64;
    const int k0 = (z ? blockIdx.x : blockIdx.y) * 64;
    const int tid = threadIdx.x;
    #pragma unroll
    for (int it = 0; it < 16; ++it) {
        int idx = it * 256 + tid;
        int r = idx >> 6, c = idx & 63;
        tile[r][c] = (bf16)ldin(src, eoff + (size_t)(k0 + r) * N + (n0 + c), isb);
    }
    __syncthreads();
    #pragma unroll
    for (int it = 0; it < 16; ++it) {
        int idx = it * 256 + tid;
        int r = idx >> 6, c = idx & 63;
        d[(size_t)(n0 + r) * K + (k0 + c)] = tile[c][r];
    }
}

// ---------------- GEMM (store epilogue): C = A @ Bt^T + bias ----------------
// 128x128 tile, BK=64, 4 waves, global_load_lds staging.
// mode 0: outb = bf16((acc+bias)*(col<scale_cols?0.125:1));  mode 1: outb = bf16(relu(acc+bias))
template<int AM>
__global__ __launch_bounds__(256, 4) void gemm_kernel(
    const void* __restrict__ A, int a_f32, const bf16* __restrict__ Bt,
    const float* __restrict__ bias, bf16* __restrict__ outb,
    int M, int N, int K, int mode, int scale_cols)
{
    constexpr int BM = AM * 32;
    constexpr int BN = 128;
    __shared__ __align__(16) bf16 smem[(BM + BN) * 64];
    bf16* As = smem;
    bf16* Bs = smem + BM * 64;

    const int tid = threadIdx.x;
    const int m0 = blockIdx.y * BM, n0 = blockIdx.x * BN;
    const int lane = tid & 63, wave = tid >> 6;
    const int wr = (wave >> 1) * (AM * 16), wc = (wave & 1) * 64;
    const int l16 = lane & 15, quad = lane >> 4;
    const int lrow = lane >> 3, lcol = (lane & 7) * 8;

    floatx4 acc[AM][4];
    #pragma unroll
    for (int i = 0; i < AM; ++i)
        #pragma unroll
        for (int j = 0; j < 4; ++j)
            #pragma unroll
            for (int r = 0; r < 4; ++r) acc[i][j][r] = 0.f;

    for (int k0 = 0; k0 < K; k0 += 64) {
        if (a_f32) {
            const float* Af = (const float*)A;
            #pragma unroll
            for (int it = 0; it < AM; ++it) {
                int chunk = it * 256 + tid;
                int row = chunk >> 3, c8 = (chunk & 7) * 8;
                size_t off = (size_t)(m0 + row) * K + k0 + c8;
                float4 f0 = *(const float4*)&Af[off];
                float4 f1 = *(const float4*)&Af[off + 4];
                bf16x8 v;
                v[0] = (bf16)f0.x; v[1] = (bf16)f0.y; v[2] = (bf16)f0.z; v[3] = (bf16)f0.w;
                v[4] = (bf16)f1.x; v[5] = (bf16)f1.y; v[6] = (bf16)f1.z; v[7] = (bf16)f1.w;
                *(bf16x8*)&As[row * 64 + c8] = v;
            }
            for (int s = wave; s < BN / 8; s += 4) {
                const bf16* gp = Bt + (size_t)(n0 + s * 8 + lrow) * K + k0 + lcol;
                GLOAD_LDS16(gp, Bs + s * 512);
            }
        } else {
            const bf16* Ab = (const bf16*)A;
            for (int s = wave; s < (BM + BN) / 8; s += 4) {
                const bf16* gp; bf16* lp;
                if (s < BM / 8) {
                    gp = Ab + (size_t)(m0 + s * 8 + lrow) * K + k0 + lcol;
                    lp = As + s * 512;
                } else {
                    int s2 = s - BM / 8;
                    gp = Bt + (size_t)(n0 + s2 * 8 + lrow) * K + k0 + lcol;
                    lp = Bs + s2 * 512;
                }
                GLOAD_LDS16(gp, lp);
            }
        }
        __syncthreads();
        #pragma unroll
        for (int kk = 0; kk < 64; kk += 32) {
            bf16x8 af[AM], bv[4];
            #pragma unroll
            for (int i = 0; i < AM; ++i) af[i] = *(const bf16x8*)&As[(wr + i * 16 + l16) * 64 + kk + quad * 8];
            #pragma unroll
            for (int j = 0; j < 4; ++j)  bv[j] = *(const bf16x8*)&Bs[(wc + j * 16 + l16) * 64 + kk + quad * 8];
            #pragma unroll
            for (int i = 0; i < AM; ++i)
                #pragma unroll
                for (int j = 0; j < 4; ++j)
                    acc[i][j] = MFMA16(af[i], bv[j], acc[i][j]);
        }
        __syncthreads();
    }

    #pragma unroll
    for (int j = 0; j < 4; ++j) {
        int col = n0 + wc + j * 16 + l16;
        float bs = bias[col];
        float alpha = (col < scale_cols) ? 0.125f : 1.0f;
        #pragma unroll
        for (int i = 0; i < AM; ++i) {
            #pragma unroll
            for (int r = 0; r < 4; ++r) {
                int row = m0 + wr + i * 16 + quad * 4 + r;
                size_t idx = (size_t)row * N + col;
                float v = (acc[i][j][r] + bs) * alpha;
                if (mode == 0) outb[idx] = (bf16)v;
                else           outb[idx] = (bf16)fmaxf(v, 0.f);
            }
        }
    }
}

// ---------------- GEMM split-K (atomic epilogue): outf += A @ Bt^T (+bias on z==0) -------
// 128x128 tile, grid.z = 2 K-splits. bf16 A only.
__global__ __launch_bounds__(256, 4) void gemm_sk_kernel(
    const bf16* __restrict__ A, const bf16* __restrict__ Bt,
    const float* __restrict__ bias, float* __restrict__ outf,
    int M, int N, int K)
{
    constexpr int BM = 128, BN = 128;
    __shared__ __align__(16) bf16 smem[(BM + BN) * 64];
    bf16* As = smem;
    bf16* Bs = smem + BM * 64;

    const int tid = threadIdx.x;
    const int m0 = blockIdx.y * BM, n0 = blockIdx.x * BN;
    const int kbeg = blockIdx.z * (K >> 1), kend = kbeg + (K >> 1);
    const int lane = tid & 63, wave = tid >> 6;
    const int wr = (wave >> 1) * 64, wc = (wave & 1) * 64;
    const int l16 = lane & 15, quad = lane >> 4;
    const int lrow = lane >> 3, lcol = (lane & 7) * 8;

    floatx4 acc[4][4];
    #pragma unroll
    for (int i = 0; i < 4; ++i)
        #pragma unroll
        for (int j = 0; j < 4; ++j)
            #pragma unroll
            for (int r = 0; r < 4; ++r) acc[i][j][r] = 0.f;

    for (int k0 = kbeg; k0 < kend; k0 += 64) {
        for (int s = wave; s < 32; s += 4) {
            const bf16* gp; bf16* lp;
            if (s < 16) {
                gp = A + (size_t)(m0 + s * 8 + lrow) * K + k0 + lcol;
                lp = As + s * 512;
            } else {
                int s2 = s - 16;
                gp = Bt + (size_t)(n0 + s2 * 8 + lrow) * K + k0 + lcol;
                lp = Bs + s2 * 512;
            }
            GLOAD_LDS16(gp, lp);
        }
        __syncthreads();
        #pragma unroll
        for (int kk = 0; kk < 64; kk += 32) {
            bf16x8 af[4], bv[4];
            #pragma unroll
            for (int i = 0; i < 4; ++i) af[i] = *(const bf16x8*)&As[(wr + i * 16 + l16) * 64 + kk + quad * 8];
            #pragma unroll
            for (int j = 0; j < 4; ++j) bv[j] = *(const bf16x8*)&Bs[(wc + j * 16 + l16) * 64 + kk + quad * 8];
            #pragma unroll
            for (int i = 0; i < 4; ++i)
                #pragma unroll
                for (int j = 0; j < 4; ++j)
                    acc[i][j] = MFMA16(af[i], bv[j], acc[i][j]);
        }
        __syncthreads();
    }

    const float bscale = (blockIdx.z == 0) ? 1.f : 0.f;
    #pragma unroll
    for (int j = 0; j < 4; ++j) {
        int col = n0 + wc + j * 16 + l16;
        float bs = bias[col] * bscale;
        #pragma unroll
        for (int i = 0; i < 4; ++i) {
            #pragma unroll
            for (int r = 0; r < 4; ++r) {
                int row = m0 + wr + i * 16 + quad * 4 + r;
                atomAddF(&outf[(size_t)row * N + col], acc[i][j][r] + bs);
            }
        }
    }
}

// ---------------- banded flash attention: x += attn, xb = bf16(x) ----------------
// LDS 52.6 KB -> 3 blocks/CU. Vt/Ps padded (+8 elem per 8 rows) -> 2-way (free) scatter writes.
#define VOFF(d) ((d) * 136 + ((d) >> 3) * 8)
#define POFF(q) ((q) * 72 + ((q) >> 3) * 8)
__global__ __launch_bounds__(256, 3) void attn_kernel(const bf16* __restrict__ qkv,
                                                      float* __restrict__ x,
                                                      bf16* __restrict__ xb)
{
    __shared__ __align__(16) bf16 Ks[128 * 64];        // [key][d] unpadded (global_load_lds)
    __shared__ __align__(16) bf16 Vt[64 * 136 + 64];   // [d][key] B-operand, padded
    __shared__ __align__(16) bf16 Ps[128 * 72 + 128];  // [q][key-half] A-operand, padded

    const int c = blockIdx.x, h = blockIdx.y, b = blockIdx.z;
    const int tid = threadIdx.x;
    const int lane = tid & 63, w = tid >> 6;
    const int l16 = lane & 15, quad = lane >> 4;
    const int lrow = lane >> 3, lcol = (lane & 7) * 8;
    const size_t rowbase = (size_t)(b * 4096 + c * 128);

    // Q fragments in registers
    bf16x8 aq[2][2];
    #pragma unroll
    for (int i = 0; i < 2; ++i)
        #pragma unroll
        for (int kh = 0; kh < 2; ++kh)
            aq[i][kh] = *(const bf16x8*)&qkv[(rowbase + w * 32 + i * 16 + l16) * 2304 + h * 64 + kh * 32 + quad * 8];

    floatx4 o[2][4], mr[2], lr[2];
    #pragma unroll
    for (int i = 0; i < 2; ++i) {
        #pragma unroll
        for (int r = 0; r < 4; ++r) { mr[i][r] = NEG_SENT; lr[i][r] = 0.f; }
        #pragma unroll
        for (int tv = 0; tv < 4; ++tv)
            #pragma unroll
            for (int r = 0; r < 4; ++r) o[i][tv][r] = 0.f;
    }

    const int t0 = (c == 0) ? 1 : 0;
    const int t1 = (c == 31) ? 1 : 2;
    for (int t = t0; t <= t1; ++t) {
        const size_t kb = (size_t)(b * 4096 + c * 128 + (t - 1) * 128);
        __syncthreads();  // prev iteration's readers done
        for (int s = w; s < 16; s += 4) {
            const bf16* gp = &qkv[(kb + s * 8 + lrow) * 2304 + 768 + h * 64 + lcol];
            GLOAD_LDS16(gp, Ks + s * 512);
        }
        // V: vectorized 16B reads, conflict-free scatter to [d][key]
        #pragma unroll
        for (int it = 0; it < 4; ++it) {
            int tsk = it * 256 + tid;
            int cc = tsk & 7, key = tsk >> 3;
            bf16x8 v = *(const bf16x8*)&qkv[(kb + key) * 2304 + 1536 + h * 64 + cc * 8];
            #pragma unroll
            for (int j = 0; j < 8; ++j) Vt[VOFF(cc * 8 + j) + key] = v[j];
        }
        __syncthreads();

        // S = Q K^T
        floatx4 st[2][8];
        #pragma unroll
        for (int i = 0; i < 2; ++i)
            #pragma unroll
            for (int j = 0; j < 8; ++j)
                #pragma unroll
                for (int r = 0; r < 4; ++r) st[i][j][r] = 0.f;
        #pragma unroll
        for (int kh = 0; kh < 2; ++kh) {
            #pragma unroll
            for (int j = 0; j < 8; ++j) {
                bf16x8 bk = *(const bf16x8*)&Ks[(j * 16 + l16) * 64 + kh * 32 + quad * 8];
                st[0][j] = MFMA16(aq[0][kh], bk, st[0][j]);
                st[1][j] = MFMA16(aq[1][kh], bk, st[1][j]);
            }
        }
        if (t != 1) {
            #pragma unroll
            for (int i = 0; i < 2; ++i)
                #pragma unroll
                for (int j = 0; j < 8; ++j)
                    #pragma unroll
                    for (int r = 0; r < 4; ++r) {
                        int qi = w * 32 + i * 16 + quad * 4 + r;
                        int ki = j * 16 + l16;
                        bool valid = (t == 0) ? (ki >= qi) : (ki <= qi);
                        if (!valid) st[i][j][r] = NEG_SENT;
                    }
        }
        // online softmax prep
        floatx4 scale[2], psum[2];
        #pragma unroll
        for (int i = 0; i < 2; ++i) {
            floatx4 mx = st[i][0];
            #pragma unroll
            for (int j = 1; j < 8; ++j)
                #pragma unroll
                for (int r = 0; r < 4; ++r) mx[r] = fmaxf(mx[r], st[i][j][r]);
            #pragma unroll
            for (int r = 0; r < 4; ++r) {
                float v = mx[r];
                #pragma unroll
                for (int off = 1; off < 16; off <<= 1) v = fmaxf(v, __shfl_xor(v, off, 64));
                float mnew = fmaxf(mr[i][r], v);
                scale[i][r] = __expf(mr[i][r] - mnew);
                mr[i][r] = mnew;
                psum[i][r] = 0.f;
            }
            #pragma unroll
            for (int tv = 0; tv < 4; ++tv)
                #pragma unroll
                for (int r = 0; r < 4; ++r) o[i][tv][r] *= scale[i][r];
        }
        // two 64-key phases: write P-half (wave-private, no barrier), then PV
        #pragma unroll
        for (int ph = 0; ph < 2; ++ph) {
            #pragma unroll
            for (int i = 0; i < 2; ++i)
                #pragma unroll
                for (int j4 = 0; j4 < 4; ++j4)
                    #pragma unroll
                    for (int r = 0; r < 4; ++r) {
                        float p = __expf(st[i][ph * 4 + j4][r] - mr[i][r]);
                        psum[i][r] += p;
                        Ps[POFF(w * 32 + i * 16 + quad * 4 + r) + j4 * 16 + l16] = (bf16)p;
                    }
            #pragma unroll
            for (int kk2 = 0; kk2 < 64; kk2 += 32) {
                bf16x8 ap0 = *(const bf16x8*)&Ps[POFF(w * 32 + l16) + kk2 + quad * 8];
                bf16x8 ap1 = *(const bf16x8*)&Ps[POFF(w * 32 + 16 + l16) + kk2 + quad * 8];
                #pragma unroll
                for (int tv = 0; tv < 4; ++tv) {
                    bf16x8 bv = *(const bf16x8*)&Vt[VOFF(tv * 16 + l16) + ph * 64 + kk2 + quad * 8];
                    o[0][tv] = MFMA16(ap0, bv, o[0][tv]);
                    o[1][tv] = MFMA16(ap1, bv, o[1][tv]);
                }
            }
        }
        // l update
        #pragma unroll
        for (int i = 0; i < 2; ++i)
            #pragma unroll
            for (int r = 0; r < 4; ++r) {
                float v = psum[i][r];
                #pragma unroll
                for (int off = 1; off < 16; off <<= 1) v += __shfl_xor(v, off, 64);
                lr[i][r] = lr[i][r] * scale[i][r] + v;
            }
    }

    // epilogue: normalize, residual add (disjoint cols per h), mirror to xb
    #pragma unroll
    for (int i = 0; i < 2; ++i)
        #pragma unroll
        for (int r = 0; r < 4; ++r) {
            int srow = w * 32 + i * 16 + quad * 4 + r;
            size_t base = (rowbase + srow) * 768 + h * 64;
            float inv = 1.f / lr[i][r];
            #pragma unroll
            for (int tv = 0; tv < 4; ++tv) {
                size_t idx = base + tv * 16 + l16;
                float val = x[idx] + o[i][tv][r] * inv;
                x[idx] = val;
                if (xb) xb[idx] = (bf16)val;
            }
        }
}

// ---------------- LayerNorm D=768, fp32 residual, optional bf16 mirror ----------------
__global__ __launch_bounds__(256) void ln_kernel(const float* in,
                                                 const float* __restrict__ g,
                                                 const float* __restrict__ be,
                                                 float* out, bf16* outb)
{
    const int wv = threadIdx.x >> 6, lane = threadIdx.x & 63;
    const size_t row = (size_t)blockIdx.x * 4 + wv;
    const float* r = in + row * 768;
    float v[12], s = 0.f, sq = 0.f;
    #pragma unroll
    for (int j = 0; j < 12; ++j) {
        float t = r[j * 64 + lane];
        v[j] = t; s += t; sq += t * t;
    }
    #pragma unroll
    for (int off = 1; off < 64; off <<= 1) {
        s += __shfl_xor(s, off, 64);
        sq += __shfl_xor(sq, off, 64);
    }
    const float mu = s * (1.f / 768.f);
    const float var = sq * (1.f / 768.f) - mu * mu;
    const float rs = rsqrtf(var + 1e-6f);
    #pragma unroll
    for (int j = 0; j < 12; ++j) {
        int col = j * 64 + lane;
        float y = (v[j] - mu) * rs * g[col] + be[col];
        out[row * 768 + col] = y;
        if (outb) outb[row * 768 + col] = (bf16)y;
    }
}

// final LN -> d_out in flag-selected dtype
__global__ __launch_bounds__(256) void ln_final_kernel(const float* __restrict__ in,
                                                       const float* __restrict__ g,
                                                       const float* __restrict__ be,
                                                       void* __restrict__ out,
                                                       const int* __restrict__ flag)
{
    const int isb = *flag;
    const int wv = threadIdx.x >> 6, lane = threadIdx.x & 63;
    const size_t row = (size_t)blockIdx.x * 4 + wv;
    const float* r = in + row * 768;
    float v[12], s = 0.f, sq = 0.f;
    #pragma unroll
    for (int j = 0; j < 12; ++j) {
        float t = r[j * 64 + lane];
        v[j] = t; s += t; sq += t * t;
    }
    #pragma unroll
    for (int off = 1; off < 64; off <<= 1) {
        s += __shfl_xor(s, off, 64);
        sq += __shfl_xor(sq, off, 64);
    }
    const float mu = s * (1.f / 768.f);
    const float var = sq * (1.f / 768.f) - mu * mu;
    const float rs = rsqrtf(var + 1e-6f);
    #pragma unroll
    for (int j = 0; j < 12; ++j) {
        int col = j * 64 + lane;
        float y = (v[j] - mu) * rs * g[col] + be[col];
        if (isb) ((bf16*)out)[row * 768 + col] = (bf16)y;
        else     ((float*)out)[row * 768 + col] = y;
    }
}

// ---------------- host ----------------
extern "C" void kernel_launch(void* const* d_in, const int* in_sizes, int n_in,
                              void* d_out, int out_size, void* d_ws, size_t ws_size,
                              hipStream_t stream)
{
    const void* src  = d_in[0];
    const void* Wq   = d_in[1];
    const void* bq   = d_in[2];
    const void* Wk   = d_in[3];
    const void* bk   = d_in[4];
    const void* Wv   = d_in[5];
    const void* bv   = d_in[6];
    const void* W1   = d_in[7];
    const void* b1   = d_in[8];
    const void* W2   = d_in[9];
    const void* b2   = d_in[10];
    const void* ln2g = d_in[11];
    const void* ln2b = d_in[12];
    const void* lnfg = d_in[13];
    const void* lnfb = d_in[14];

    const size_t SZ_X   = 8192ull * 768 * 4;   // 25,165,824
    const size_t SZ_XB  = 8192ull * 768 * 2;   // 12,582,912
    const size_t SZ_QKV = 8192ull * 2304 * 2;  // 37,748,736
    const size_t SZ_H1F = 8192ull * 3072 * 2;  // 50,331,648
    const size_t SZ_W1  = 3072ull * 768 * 2;   //  4,718,592 (also holds qkvT 3.5MB)
    const size_t SZ_W2  = 4718592;
    const size_t SMALL  = 131072;
    const size_t needA = SZ_X + SZ_XB + SZ_H1F + SZ_W1 + SZ_W2 + SMALL;  // 97,648,640 (proven fits, r5)
    const size_t needB = SZ_X + SZ_XB + SZ_QKV + SZ_W1 + SZ_W2 + SMALL;
    const int lay = (ws_size >= needA) ? 2 : (ws_size >= needB) ? 1 : 0;

    char* p = (char*)d_ws;
    float* x = (float*)p;  p += SZ_X;
    bf16* xb = nullptr;
    if (lay) { xb = (bf16*)p; p += SZ_XB; }
    bf16* sh  = (bf16*)p;  p += (lay == 2) ? SZ_H1F : SZ_QKV;
    bf16* wT  = (bf16*)p;  p += SZ_W1;
    bf16* w2T = (bf16*)p;  p += SZ_W2;
    float* sm = (float*)p;
    float* qbias = sm;          float* b1c = sm + 9216;   float* b2c = sm + 21504;
    float* ln2gc = sm + 24576;  float* ln2bc = sm + 27648;
    float* lnfgc = sm + 30720;  float* lnfbc = sm + 31488;
    int* flag = (int*)(sm + 32256);

    sniff_kernel<<<1, 256, 0, stream>>>((const unsigned short*)src, flag);
    cvt_src_kernel<<<1024, 256, 0, stream>>>(src, x, xb, 8192 * 768, flag);
    prep_kernel<<<126, 256, 0, stream>>>(bq, bk, bv, b1, b2, ln2g, ln2b, lnfg, lnfb, sm, flag);

    for (int i = 0; i < 4; ++i) {
        const size_t woQ = (size_t)i * 768 * 768;
        const size_t wo1 = (size_t)i * 768 * 3072;
        const size_t wo2 = (size_t)i * 3072 * 768;

        transpose3_kernel<<<dim3(12, 12, 3), 256, 0, stream>>>(Wq, Wk, Wv, woQ, wT, flag);

        if (lay)
            gemm_kernel<4><<<dim3(18, 64), 256, 0, stream>>>(xb, 0, wT, qbias + i * 2304,
                                                             sh, 8192, 2304, 768, 0, 768);
        else
            gemm_kernel<4><<<dim3(18, 64), 256, 0, stream>>>(x, 1, wT, qbias + i * 2304,
                                                             sh, 8192, 2304, 768, 0, 768);
        attn_kernel<<<dim3(32, 12, 2), 256, 0, stream>>>(sh, x, xb);

        transpose12_kernel<<<dim3(48, 12, 2), 256, 0, stream>>>(W1, wo1, wT, W2, wo2, w2T, flag);

        if (lay == 2) {
            gemm_kernel<4><<<dim3(24, 64), 256, 0, stream>>>(xb, 0, wT, b1c + i * 3072,
                                                             sh, 8192, 3072, 768, 1, 0);
            gemm_sk_kernel<<<dim3(6, 64, 2), 256, 0, stream>>>(sh, w2T, b2c + i * 768,
                                                               x, 8192, 768, 3072);
        } else {
            for (int half = 0; half < 2; ++half) {
                float* xh = x + (size_t)half * 4096 * 768;
                const void* A1 = lay ? (const void*)(xb + (size_t)half * 4096 * 768) : (const void*)xh;
                gemm_kernel<4><<<dim3(24, 32), 256, 0, stream>>>(A1, lay ? 0 : 1, wT, b1c + i * 3072,
                                                                 sh, 4096, 3072, 768, 1, 0);
                gemm_sk_kernel<<<dim3(6, 32, 2), 256, 0, stream>>>(sh, w2T, b2c + i * 768,
                                                                   xh, 4096, 768, 3072);
            }
        }
        ln_kernel<<<2048, 256, 0, stream>>>(x, ln2gc + i * 768, ln2bc + i * 768, x, xb);
    }
    ln_final_kernel<<<2048, 256, 0, stream>>>(x, lnfgc, lnfbc, d_out, flag);
}